// Round 17
// baseline (995.761 us; speedup 1.0000x reference)
//
#include <hip/hip_runtime.h>

#define B_ 8
#define N_ 4096
#define K_ 1024
#define NN_ 16
#define C1_ 128
#define C2_ 128
#define CIN_ 67
#define NROWS (B_*K_*NN_)   // 131072
#define NBLK2 (NROWS/128)   // 1024 gemm2 tiles (128-row retile)
#define BN_N 131072.0f

typedef unsigned short u16;
typedef unsigned long long u64;

// BN accumulators, 8-way slot-spread (r18: 1M atomics on 256 addresses cost
// ~150 us of L2 same-address serialization; slot = blk&7 cuts it 8x).
__device__ float g_statsA[8*256];               // BN1 sum/sumsq per slot
__device__ float g_statsB[8*256];               // BN2 sum/sumsq per slot
__device__ float g_m2[B_*K_*C2_];
// W1^T PERMUTED row order: q<64 -> points channel 3+q; q 64..66 -> xyz
// channel q-64; q=67 -> 0. Matches Xs layout (points 0-63, xyz 64-66,
// zero 67) so staging is float4/b128 aligned.
__device__ float g_W1T[68*128];
__device__ float g_W2T[128*128];                // W2^T [q][o]
__device__ __align__(16) float g_h1[(size_t)NROWS*128];   // pre-BN1 h1 (64 MB)

// --------------------------------------------------- DPP wave reduction ----
// Value-only max reduce-to-lane-63 (12 inst). Index resolved via ballot +
// ffs + readlane — exact for fps (blocked ascending per-lane index ranges).
template<int CTRL>
static __device__ __forceinline__ void dpp_maxv_step(float& v) {
    int vi = __float_as_int(v);
    int ov = __builtin_amdgcn_update_dpp(vi, vi, CTRL, 0xf, 0xf, false);
    v = fmaxf(v, __int_as_float(ov));
}
static __device__ __forceinline__ void wave_reduce_maxval(float& v) {
    dpp_maxv_step<0x111>(v);
    dpp_maxv_step<0x112>(v);
    dpp_maxv_step<0x114>(v);
    dpp_maxv_step<0x118>(v);
    dpp_maxv_step<0x142>(v);
    dpp_maxv_step<0x143>(v);   // lane 63 holds max
}
// kNN keeps the lexicographic pair reduce (its indices are interleaved).
template<int CTRL>
static __device__ __forceinline__ void dpp_min_step(float& v, int& ib) {
    int vi = __float_as_int(v);
    int ov = __builtin_amdgcn_update_dpp(vi, vi, CTRL, 0xf, 0xf, false);
    int oi = __builtin_amdgcn_update_dpp(ib, ib, CTRL, 0xf, 0xf, false);
    float of = __int_as_float(ov);
    if (of < v || (of == v && oi < ib)) { v = of; ib = oi; }
}
static __device__ __forceinline__ void wave_reduce_min(float& v, int& ib) {
    dpp_min_step<0x111>(v, ib);
    dpp_min_step<0x112>(v, ib);
    dpp_min_step<0x114>(v, ib);
    dpp_min_step<0x118>(v, ib);
    dpp_min_step<0x142>(v, ib);
    dpp_min_step<0x143>(v, ib);
}

// ------------------------------------- weight transpose + stats zeroing ----
__global__ void transpose_w_kernel(const float* __restrict__ W1,
                                   const float* __restrict__ W2) {
    int t = blockIdx.x * 256 + threadIdx.x;
    if (t < 8*256) { g_statsA[t] = 0.f; g_statsB[t] = 0.f; }
    if (t < 68*128) {
        int q = t >> 7, o = t & 127;
        float v;
        if (q < 64)      v = W1[o*CIN_ + 3 + q];      // points channels
        else if (q < 67) v = W1[o*CIN_ + (q - 64)];   // xyz channels
        else             v = 0.f;
        g_W1T[t] = v;
    }
    if (t < 128*128) {
        int q = t >> 7, o = t & 127;
        g_W2T[t] = W2[o*C1_ + q];
    }
}

// ---------------------------------------------------------------- FPS ------
// FROZEN at the r10/r13-proven structure (608-612 us, passed 5x): v9 body +
// packed-u64 atomicMax tail. Structural floor evidence: r10 (tail op-count
// neutral), r14 (2 waves/SIMD +30 us — barrier-lockstep leaves nothing to
// overlap), v10/v12/v13 (state growth -> remat/spill), 1024-thr variant
// wedges containers (r11/r12, quarantined). 1430 cyc/step is irreducible
// at HIP level; VALUBusy 1.7% / hbm 0.007% = serial-latency floor.
__global__ __launch_bounds__(256) void fps_kernel(const float* __restrict__ xyz,
                                                  float* __restrict__ out_xyz) {
    __shared__ float sx[N_*3];       // 48 KB xyz copy
    __shared__ float sout[K_*3];     // 12 KB selected centroids
    __shared__ u64   slot[4];
    const int b = blockIdx.x, t = threadIdx.x;
    const int l = t & 63, w = t >> 6;
    (void)w;
    const float* xb = xyz + b * (N_ * 3);
    for (int e = t; e < N_*3; e += 256) sx[e] = xb[e];
    if (t < 4) slot[t] = 0ull;
    __syncthreads();
    float x0[16], y0[16], z0[16], dist[16];
    #pragma unroll
    for (int j = 0; j < 16; ++j) {
        int p = t * 16 + j;
        x0[j] = sx[p*3+0]; y0[j] = sx[p*3+1]; z0[j] = sx[p*3+2];
        dist[j] = 1e10f;
    }
    int far = 0;
    for (int s = 0; s < K_; ++s) {
        const float cx = sx[far*3+0], cy = sx[far*3+1], cz = sx[far*3+2];
        if (t == 0) {
            sout[s*3+0] = cx; sout[s*3+1] = cy; sout[s*3+2] = cz;
        }
        float v = -1.f; int ib = 0;
        {
            #pragma clang fp contract(fast)
            #pragma unroll
            for (int j = 0; j < 16; ++j) {
                float dx = x0[j]-cx, dy = y0[j]-cy, dz = z0[j]-cz;
                float dd = dx*dx + dy*dy + dz*dz;
                dd = fminf(dist[j], dd);
                dist[j] = dd;
                if (dd > v) { v = dd; ib = t*16 + j; }   // ascending j: first max
            }
        }
        float vr = v;
        wave_reduce_maxval(vr);
        const float m = __int_as_float(__builtin_amdgcn_readlane(__float_as_int(vr), 63));
        unsigned long long mk = __ballot(v == m);
        const int ln  = __ffsll((unsigned long long)mk) - 1;   // lowest tied lane
        const int wib = __builtin_amdgcn_readlane(ib, ln);
        if (l == 0) {
            u64 pk = ((u64)(unsigned)__float_as_int(m) << 32) | (unsigned)(4095 - wib);
            atomicMax(&slot[s & 3], pk);
        }
        if (t == 0) slot[(s + 2) & 3] = 0ull;   // rotation: r10 proof
        __syncthreads();                   // only barrier per step
        u64 pk = slot[s & 3];
        far = 4095 - ((unsigned)pk & 4095);
    }
    __syncthreads();                       // sout complete
    for (int e = t; e < K_*3; e += 256) out_xyz[b*K_*3 + e] = sout[e];
}

// ------------------------------------------- fused kNN + GEMM1/stats ------
// r16 fusion (-21 us proven): one knn block (4 centers) == one 64-row
// stats1 tile. r17: INCREMENTAL selection — after each round only the
// winner-owner lane's local min changes (owner = win & 63, since
// p = j*64 + l). Maintain per-lane (lv, li); per round = DPP reduce +
// owner-only poison-and-rescan (one combined pass). Ordering identical to
// full rescan of the poisoned array (same lexicographic (d,p) minima).
// ~-30% selection instructions; issue-bound (r6) so ~linear in time.
__global__ __launch_bounds__(256) void knn_stats1_kernel(
        const float* __restrict__ xyz, const float* __restrict__ points,
        const float* __restrict__ newxyz, const float* __restrict__ b1) {
    __shared__ union {
        struct { float px[N_], py[N_], pz[N_]; } a;     // knn staging (48 KB)
        union {
            float Xs[64][68];                            // GEMM1 operand
            struct { float ps[16][128], pq[16][128]; } c;
        } b;
    } u;
    __shared__ float cen[4][3];
    __shared__ u16   kn[64];
    const int bb = blockIdx.y, t = threadIdx.x;
    const int l = t & 63, w = t >> 6;
    const int blk = bb*256 + blockIdx.x;    // global tile id, 0..2047
    const int g0 = blk * 64;
    const float* xb = xyz + bb * (N_ * 3);
    // ---- stage xyz (r9-vectorized: 3 float4 -> 4 points) ----
    #pragma unroll
    for (int kk = 0; kk < 4; ++kk) {
        const int p0 = (t + kk*256) * 4;
        const float4* s = (const float4*)(xb + (size_t)p0*3);
        float4 a4 = s[0], bq = s[1], c4 = s[2];
        u.a.px[p0+0]=a4.x;  u.a.py[p0+0]=a4.y;  u.a.pz[p0+0]=a4.z;
        u.a.px[p0+1]=a4.w;  u.a.py[p0+1]=bq.x;  u.a.pz[p0+1]=bq.y;
        u.a.px[p0+2]=bq.z;  u.a.py[p0+2]=bq.w;  u.a.pz[p0+2]=c4.x;
        u.a.px[p0+3]=c4.y;  u.a.py[p0+3]=c4.z;  u.a.pz[p0+3]=c4.w;
    }
    if (t < 12) cen[t/3][t%3] = newxyz[(bb*K_ + blockIdx.x*4 + t/3)*3 + (t%3)];
    __syncthreads();
    // ---- kNN phase ----
    const float cx = cen[w][0], cy = cen[w][1], cz = cen[w][2];
    float d[64];
    {
        #pragma clang fp contract(off)
        float sn = cx*cx; sn = sn + cy*cy; sn = sn + cz*cz;
        #pragma unroll
        for (int j = 0; j < 64; ++j) {
            int p = j*64 + l;
            float X = u.a.px[p], Y = u.a.py[p], Z = u.a.pz[p];
            float sp = X*X; sp = sp + Y*Y; sp = sp + Z*Z;
            float dt = cx*X; dt = dt + cy*Y; dt = dt + cz*Z;
            float t1 = sn + sp;
            d[j] = t1 - 2.0f*dt;
        }
    }
    // initial per-lane local min
    float lv = 1e38f; int li = 0x7fffffff;
    #pragma unroll
    for (int j = 0; j < 64; ++j) {
        int p = j*64 + l;
        bool lt = (d[j] < lv) || (d[j] == lv && p < li);
        if (lt) { lv = d[j]; li = p; }
    }
    for (int r = 0; r < NN_; ++r) {
        float bv = lv; int bi = li;            // copies: reduce is destructive
        wave_reduce_min(bv, bi);
        const int win = __builtin_amdgcn_readlane(bi, 63);
        if (l == 0) kn[w*16 + r] = (u16)(win & 4095);
        if ((win & 63) == l) {
            // I own the winner: poison it and recompute my local min (one pass)
            lv = 1e38f; li = 0x7fffffff;
            #pragma unroll
            for (int j = 0; j < 64; ++j) {
                int p = j*64 + l;
                float vj = d[j];
                if (p == win) { vj = 1e38f; d[j] = vj; }
                bool lt = (vj < lv) || (vj == lv && p < li);
                if (lt) { lv = vj; li = p; }
            }
        }
    }
    __syncthreads();                 // selection done everywhere; kn complete
    // ---- neighbor xyz from staged LDS -> registers (before overwrite) ----
    float rx = 0.f, ry = 0.f, rz = 0.f;
    if (t < 64) {
        int rp = (int)kn[t];
        rx = u.a.px[rp]; ry = u.a.py[rp]; rz = u.a.pz[rp];
    }
    __syncthreads();                 // px/py/pz reads complete -> union free
    // ---- Xs fill: points cols 0-63 (4 thr/row x 4 float4), xyz 64-66 ----
    {
        const int r = t >> 2, q = t & 3;
        const int p = (int)kn[r];
        const float* src = points + ((size_t)(bb*N_ + p))*64 + q*16;
        float4 v0 = *(const float4*)(src + 0);
        float4 v1 = *(const float4*)(src + 4);
        float4 v2 = *(const float4*)(src + 8);
        float4 v3 = *(const float4*)(src + 12);
        *(float4*)&u.b.Xs[r][q*16 + 0]  = v0;
        *(float4*)&u.b.Xs[r][q*16 + 4]  = v1;
        *(float4*)&u.b.Xs[r][q*16 + 8]  = v2;
        *(float4*)&u.b.Xs[r][q*16 + 12] = v3;
    }
    if (t < 64) {
        u.b.Xs[t][64] = rx - cen[t >> 4][0];
        u.b.Xs[t][65] = ry - cen[t >> 4][1];
        u.b.Xs[t][66] = rz - cen[t >> 4][2];
        u.b.Xs[t][67] = 0.f;
    }
    __syncthreads();
    // ---- GEMM1 (r9 64-row shape: 4 rows/thread, acc[4][8]) ----
    const int rg = t >> 4, cg = t & 15;
    const int r0 = rg * 4;
    float acc[4][8];
    #pragma unroll
    for (int j = 0; j < 4; ++j)
        #pragma unroll
        for (int i = 0; i < 8; ++i) acc[j][i] = 0.f;
    for (int q4 = 0; q4 < 17; ++q4) {
        float4 xv[4];
        #pragma unroll
        for (int j = 0; j < 4; ++j) xv[j] = *(const float4*)&u.b.Xs[r0 + j][q4*4];
        #pragma unroll
        for (int i = 0; i < 8; ++i) {
            int o = cg + 16*i;
            float w0 = g_W1T[(q4*4+0)*128 + o];
            float w1 = g_W1T[(q4*4+1)*128 + o];
            float w2 = g_W1T[(q4*4+2)*128 + o];
            float w3 = g_W1T[(q4*4+3)*128 + o];
            #pragma unroll
            for (int j = 0; j < 4; ++j) {
                float a = acc[j][i];
                a = a + xv[j].x*w0; a = a + xv[j].y*w1;
                a = a + xv[j].z*w2; a = a + xv[j].w*w3;
                acc[j][i] = a;
            }
        }
    }
    __syncthreads();   // Xs reads done -> union reusable for ps/pq
    #pragma unroll
    for (int i = 0; i < 8; ++i) {
        int o = cg + 16*i;
        float bias = b1[o];
        float s = 0.f, sq = 0.f;
        #pragma unroll
        for (int j = 0; j < 4; ++j) {
            float v = acc[j][i] + bias;
            g_h1[(size_t)(g0 + r0 + j)*128 + o] = v;
            s += v; sq += v*v;
        }
        u.b.c.ps[rg][o] = s; u.b.c.pq[rg][o] = sq;
    }
    __syncthreads();
    if (t < 128) {
        float ts = 0.f, tq = 0.f;
        #pragma unroll
        for (int g = 0; g < 16; ++g) { ts += u.b.c.ps[g][t]; tq += u.b.c.pq[g][t]; }
        const int slot = (blk & 7) * 256;
        atomicAdd(&g_statsA[slot + t], ts);
        atomicAdd(&g_statsA[slot + 128 + t], tq);
    }
}

// ------------------------------------------------ BN1+ReLU + GEMM2 ---------
// r8 retile: 128 rows/block (1024 blocks), 8 rows/thread (proven -15 us).
__global__ __launch_bounds__(256) void gemm2_kernel(
        const float* __restrict__ b2, const float* __restrict__ g1,
        const float* __restrict__ be1) {
    __shared__ float mn1[128], sc1[128], bb1[128];
    __shared__ union {
        float h1s[128][132];
        struct { float ps[16][128], pq[16][128], pm[16][128]; } c;
    } u;
    const int t = threadIdx.x;
    const int blk = blockIdx.x;
    const int g0 = blk * 128;
    if (t < 128) {
        float sum = 0.f, sq = 0.f;
        #pragma unroll
        for (int s = 0; s < 8; ++s) {
            sum += g_statsA[s*256 + t];
            sq  += g_statsA[s*256 + 128 + t];
        }
        float mean = sum * (1.f / BN_N);
        float var  = sq * (1.f / BN_N) - mean*mean;
        mn1[t] = mean; sc1[t] = (1.f / sqrtf(var + 1e-5f)) * g1[t];
        bb1[t] = be1[t];
    }
    __syncthreads();
    for (int e = t*4; e < 128*128; e += 1024) {
        float4 hv = *(const float4*)&g_h1[(size_t)g0*128 + e];
        int r = e >> 7, c = e & 127;
        u.h1s[r][c+0] = fmaxf((hv.x - mn1[c+0])*sc1[c+0] + bb1[c+0], 0.f);
        u.h1s[r][c+1] = fmaxf((hv.y - mn1[c+1])*sc1[c+1] + bb1[c+1], 0.f);
        u.h1s[r][c+2] = fmaxf((hv.z - mn1[c+2])*sc1[c+2] + bb1[c+2], 0.f);
        u.h1s[r][c+3] = fmaxf((hv.w - mn1[c+3])*sc1[c+3] + bb1[c+3], 0.f);
    }
    __syncthreads();
    const int rg = t >> 4, cg = t & 15;
    const int r0 = rg * 8;
    float acc2[8][8];
    #pragma unroll
    for (int j = 0; j < 8; ++j)
        #pragma unroll
        for (int i = 0; i < 8; ++i) acc2[j][i] = 0.f;
    for (int q4 = 0; q4 < 32; ++q4) {
        float4 xv[8];
        #pragma unroll
        for (int j = 0; j < 8; ++j) xv[j] = *(const float4*)&u.h1s[r0 + j][q4*4];
        #pragma unroll
        for (int i = 0; i < 8; ++i) {
            int o = cg + 16*i;
            float w0 = g_W2T[(q4*4+0)*128 + o];
            float w1 = g_W2T[(q4*4+1)*128 + o];
            float w2 = g_W2T[(q4*4+2)*128 + o];
            float w3 = g_W2T[(q4*4+3)*128 + o];
            #pragma unroll
            for (int j = 0; j < 8; ++j) {
                float a = acc2[j][i];
                a = a + xv[j].x*w0; a = a + xv[j].y*w1;
                a = a + xv[j].z*w2; a = a + xv[j].w*w3;
                acc2[j][i] = a;
            }
        }
    }
    __syncthreads();   // h1s reads done -> union reusable
    #pragma unroll
    for (int i = 0; i < 8; ++i) {
        int o = cg + 16*i;
        float bias = b2[o];
        float s = 0.f, sq = 0.f, mx = -1e38f;
        #pragma unroll
        for (int j = 0; j < 8; ++j) {
            float v = acc2[j][i] + bias;
            s += v; sq += v*v; mx = fmaxf(mx, v);
        }
        u.c.ps[rg][o] = s; u.c.pq[rg][o] = sq; u.c.pm[rg][o] = mx;
    }
    __syncthreads();
    if (t < 128) {
        float ts = 0.f, tq = 0.f;
        #pragma unroll
        for (int g = 0; g < 16; ++g) { ts += u.c.ps[g][t]; tq += u.c.pq[g][t]; }
        const int slot = (blk & 7) * 256;
        atomicAdd(&g_statsB[slot + t], ts);
        atomicAdd(&g_statsB[slot + 128 + t], tq);
    }
    {
        // max-pool: 128 rows = 8 output m-rows (16 input rows each);
        // pm[rg] covers rows rg*8..rg*8+7 -> m-row gm uses rg = 2gm, 2gm+1.
        const int o = t & 127, gg = t >> 7;          // gg in {0,1}
        #pragma unroll
        for (int h = 0; h < 4; ++h) {
            const int gm = h*2 + gg;                 // 0..7
            float mx = fmaxf(u.c.pm[gm*2 + 0][o], u.c.pm[gm*2 + 1][o]);
            g_m2[(blk*8 + gm)*128 + o] = mx;
        }
    }
}

// ------------------------------------------------------------- finalize ----
__global__ __launch_bounds__(256) void final_kernel(
        const float* __restrict__ g2, const float* __restrict__ be2,
        float* __restrict__ outp) {
    __shared__ float mn[128], sc[128], bb[128];
    const int t = threadIdx.x;
    if (t < 128) {
        float sum = 0.f, sq = 0.f;
        #pragma unroll
        for (int s = 0; s < 8; ++s) {
            sum += g_statsB[s*256 + t];
            sq  += g_statsB[s*256 + 128 + t];
        }
        float mean = sum * (1.f / BN_N);
        float var  = sq * (1.f / BN_N) - mean*mean;
        float inv  = 1.f / sqrtf(var + 1e-5f);
        mn[t] = mean; sc[t] = inv * g2[t]; bb[t] = be2[t];
    }
    __syncthreads();
    const int m = blockIdx.x*2 + (t >> 7);
    const int c = t & 127;
    float v = (g_m2[m*128 + c] - mn[c]) * sc[c] + bb[c];
    v = fmaxf(v, 0.f);
    outp[m*C2_ + c] = v;
}

// -------------------------------------------------------------- launch -----
extern "C" void kernel_launch(void* const* d_in, const int* in_sizes, int n_in,
                              void* d_out, int out_size, void* d_ws, size_t ws_size,
                              hipStream_t stream) {
    const float* xyz    = (const float*)d_in[0];
    const float* points = (const float*)d_in[1];
    const float* W1     = (const float*)d_in[2];
    const float* b1     = (const float*)d_in[3];
    const float* g1     = (const float*)d_in[4];
    const float* be1    = (const float*)d_in[5];
    const float* W2     = (const float*)d_in[6];
    const float* b2     = (const float*)d_in[7];
    const float* g2     = (const float*)d_in[8];
    const float* be2    = (const float*)d_in[9];

    float* out_xyz = (float*)d_out;
    float* out_pts = (float*)d_out + B_*K_*3;

    (void)d_ws; (void)ws_size;

    transpose_w_kernel<<<64, 256, 0, stream>>>(W1, W2);   // + zeroes stats
    fps_kernel<<<B_, 256, 0, stream>>>(xyz, out_xyz);
    knn_stats1_kernel<<<dim3(256, B_), 256, 0, stream>>>(xyz, points, out_xyz, b1);
    gemm2_kernel<<<NBLK2, 256, 0, stream>>>(b2, g1, be1);
    final_kernel<<<B_*K_/2, 256, 0, stream>>>(g2, be2, out_pts);
}

// Round 18
// 978.360 us; speedup vs baseline: 1.0178x; 1.0178x over previous
//
#include <hip/hip_runtime.h>

#define B_ 8
#define N_ 4096
#define K_ 1024
#define NN_ 16
#define C1_ 128
#define C2_ 128
#define CIN_ 67
#define NROWS (B_*K_*NN_)   // 131072
#define NBLK2 (NROWS/128)   // 1024 gemm2 tiles (128-row retile)
#define BN_N 131072.0f

typedef unsigned short u16;
typedef unsigned long long u64;

// BN accumulators, 8-way slot-spread (r18: 1M atomics on 256 addresses cost
// ~150 us of L2 same-address serialization; slot = blk&7 cuts it 8x).
__device__ float g_statsA[8*256];               // BN1 sum/sumsq per slot
__device__ float g_statsB[8*256];               // BN2 sum/sumsq per slot
__device__ float g_m2[B_*K_*C2_];
// W1^T PERMUTED row order: q<64 -> points channel 3+q; q 64..66 -> xyz
// channel q-64; q=67 -> 0. Matches Xs layout (points 0-63, xyz 64-66,
// zero 67) so staging is float4/b128 aligned.
__device__ float g_W1T[68*128];
__device__ float g_W2T[128*128];                // W2^T [q][o]
__device__ __align__(16) float g_h1[(size_t)NROWS*128];   // pre-BN1 h1 (64 MB)

// --------------------------------------------------- DPP wave reduction ----
// Value-only max reduce-to-lane-63 (12 inst). Index resolved via ballot +
// ffs + readlane — exact for fps (blocked ascending per-lane index ranges).
template<int CTRL>
static __device__ __forceinline__ void dpp_maxv_step(float& v) {
    int vi = __float_as_int(v);
    int ov = __builtin_amdgcn_update_dpp(vi, vi, CTRL, 0xf, 0xf, false);
    v = fmaxf(v, __int_as_float(ov));
}
static __device__ __forceinline__ void wave_reduce_maxval(float& v) {
    dpp_maxv_step<0x111>(v);
    dpp_maxv_step<0x112>(v);
    dpp_maxv_step<0x114>(v);
    dpp_maxv_step<0x118>(v);
    dpp_maxv_step<0x142>(v);
    dpp_maxv_step<0x143>(v);   // lane 63 holds max
}
// kNN keeps the lexicographic pair reduce (its indices are interleaved).
template<int CTRL>
static __device__ __forceinline__ void dpp_min_step(float& v, int& ib) {
    int vi = __float_as_int(v);
    int ov = __builtin_amdgcn_update_dpp(vi, vi, CTRL, 0xf, 0xf, false);
    int oi = __builtin_amdgcn_update_dpp(ib, ib, CTRL, 0xf, 0xf, false);
    float of = __int_as_float(ov);
    if (of < v || (of == v && oi < ib)) { v = of; ib = oi; }
}
static __device__ __forceinline__ void wave_reduce_min(float& v, int& ib) {
    dpp_min_step<0x111>(v, ib);
    dpp_min_step<0x112>(v, ib);
    dpp_min_step<0x114>(v, ib);
    dpp_min_step<0x118>(v, ib);
    dpp_min_step<0x142>(v, ib);
    dpp_min_step<0x143>(v, ib);
}

// ------------------------------------- weight transpose + stats zeroing ----
__global__ void transpose_w_kernel(const float* __restrict__ W1,
                                   const float* __restrict__ W2) {
    int t = blockIdx.x * 256 + threadIdx.x;
    if (t < 8*256) { g_statsA[t] = 0.f; g_statsB[t] = 0.f; }
    if (t < 68*128) {
        int q = t >> 7, o = t & 127;
        float v;
        if (q < 64)      v = W1[o*CIN_ + 3 + q];      // points channels
        else if (q < 67) v = W1[o*CIN_ + (q - 64)];   // xyz channels
        else             v = 0.f;
        g_W1T[t] = v;
    }
    if (t < 128*128) {
        int q = t >> 7, o = t & 127;
        g_W2T[t] = W2[o*C1_ + q];
    }
}

// ---------------------------------------------------------------- FPS ------
// FROZEN at the r10/r13-proven structure (608-612 us, passed 6x): v9 body +
// packed-u64 atomicMax tail. Structural floor evidence: r10 (tail op-count
// neutral), r14 (2 waves/SIMD +30 us — barrier-lockstep leaves nothing to
// overlap), v10/v12/v13 (state growth -> remat/spill), 1024-thr variant
// wedges containers (r11/r12, quarantined). 1430 cyc/step is irreducible
// at HIP level; VALUBusy 1.7% / hbm 0.007% = serial-latency floor.
__global__ __launch_bounds__(256) void fps_kernel(const float* __restrict__ xyz,
                                                  float* __restrict__ out_xyz) {
    __shared__ float sx[N_*3];       // 48 KB xyz copy
    __shared__ float sout[K_*3];     // 12 KB selected centroids
    __shared__ u64   slot[4];
    const int b = blockIdx.x, t = threadIdx.x;
    const int l = t & 63, w = t >> 6;
    (void)w;
    const float* xb = xyz + b * (N_ * 3);
    for (int e = t; e < N_*3; e += 256) sx[e] = xb[e];
    if (t < 4) slot[t] = 0ull;
    __syncthreads();
    float x0[16], y0[16], z0[16], dist[16];
    #pragma unroll
    for (int j = 0; j < 16; ++j) {
        int p = t * 16 + j;
        x0[j] = sx[p*3+0]; y0[j] = sx[p*3+1]; z0[j] = sx[p*3+2];
        dist[j] = 1e10f;
    }
    int far = 0;
    for (int s = 0; s < K_; ++s) {
        const float cx = sx[far*3+0], cy = sx[far*3+1], cz = sx[far*3+2];
        if (t == 0) {
            sout[s*3+0] = cx; sout[s*3+1] = cy; sout[s*3+2] = cz;
        }
        float v = -1.f; int ib = 0;
        {
            #pragma clang fp contract(fast)
            #pragma unroll
            for (int j = 0; j < 16; ++j) {
                float dx = x0[j]-cx, dy = y0[j]-cy, dz = z0[j]-cz;
                float dd = dx*dx + dy*dy + dz*dz;
                dd = fminf(dist[j], dd);
                dist[j] = dd;
                if (dd > v) { v = dd; ib = t*16 + j; }   // ascending j: first max
            }
        }
        float vr = v;
        wave_reduce_maxval(vr);
        const float m = __int_as_float(__builtin_amdgcn_readlane(__float_as_int(vr), 63));
        unsigned long long mk = __ballot(v == m);
        const int ln  = __ffsll((unsigned long long)mk) - 1;   // lowest tied lane
        const int wib = __builtin_amdgcn_readlane(ib, ln);
        if (l == 0) {
            u64 pk = ((u64)(unsigned)__float_as_int(m) << 32) | (unsigned)(4095 - wib);
            atomicMax(&slot[s & 3], pk);
        }
        if (t == 0) slot[(s + 2) & 3] = 0ull;   // rotation: r10 proof
        __syncthreads();                   // only barrier per step
        u64 pk = slot[s & 3];
        far = 4095 - ((unsigned)pk & 4095);
    }
    __syncthreads();                       // sout complete
    for (int e = t; e < K_*3; e += 256) out_xyz[b*K_*3 + e] = sout[e];
}

// ------------------------------------------- fused kNN + GEMM1/stats ------
// r16 fusion (-21 us proven, 978.5 us total): one knn block (4 centers) ==
// one 64-row stats1 tile. Selection = r8 poison-rescan, REVERTED from
// r17's incremental variant (+17 us: one owner lane/wave always takes the
// masked rescan branch, so the wave issues the full loop anyway plus
// bookkeeping — uniform branchless scan+poison is issue-optimal here).
__global__ __launch_bounds__(256) void knn_stats1_kernel(
        const float* __restrict__ xyz, const float* __restrict__ points,
        const float* __restrict__ newxyz, const float* __restrict__ b1) {
    __shared__ union {
        struct { float px[N_], py[N_], pz[N_]; } a;     // knn staging (48 KB)
        union {
            float Xs[64][68];                            // GEMM1 operand
            struct { float ps[16][128], pq[16][128]; } c;
        } b;
    } u;
    __shared__ float cen[4][3];
    __shared__ u16   kn[64];
    const int bb = blockIdx.y, t = threadIdx.x;
    const int l = t & 63, w = t >> 6;
    const int blk = bb*256 + blockIdx.x;    // global tile id, 0..2047
    const int g0 = blk * 64;
    const float* xb = xyz + bb * (N_ * 3);
    // ---- stage xyz (r9-vectorized: 3 float4 -> 4 points) ----
    #pragma unroll
    for (int kk = 0; kk < 4; ++kk) {
        const int p0 = (t + kk*256) * 4;
        const float4* s = (const float4*)(xb + (size_t)p0*3);
        float4 a4 = s[0], bq = s[1], c4 = s[2];
        u.a.px[p0+0]=a4.x;  u.a.py[p0+0]=a4.y;  u.a.pz[p0+0]=a4.z;
        u.a.px[p0+1]=a4.w;  u.a.py[p0+1]=bq.x;  u.a.pz[p0+1]=bq.y;
        u.a.px[p0+2]=bq.z;  u.a.py[p0+2]=bq.w;  u.a.pz[p0+2]=c4.x;
        u.a.px[p0+3]=c4.y;  u.a.py[p0+3]=c4.z;  u.a.pz[p0+3]=c4.w;
    }
    if (t < 12) cen[t/3][t%3] = newxyz[(bb*K_ + blockIdx.x*4 + t/3)*3 + (t%3)];
    __syncthreads();
    // ---- kNN phase (poison-select, r8-proven) ----
    const float cx = cen[w][0], cy = cen[w][1], cz = cen[w][2];
    float d[64];
    {
        #pragma clang fp contract(off)
        float sn = cx*cx; sn = sn + cy*cy; sn = sn + cz*cz;
        #pragma unroll
        for (int j = 0; j < 64; ++j) {
            int p = j*64 + l;
            float X = u.a.px[p], Y = u.a.py[p], Z = u.a.pz[p];
            float sp = X*X; sp = sp + Y*Y; sp = sp + Z*Z;
            float dt = cx*X; dt = dt + cy*Y; dt = dt + cz*Z;
            float t1 = sn + sp;
            d[j] = t1 - 2.0f*dt;
        }
    }
    for (int r = 0; r < NN_; ++r) {
        float bv = 1e38f; int bi = 0x7fffffff;
        #pragma unroll
        for (int j = 0; j < 64; ++j) {
            int p = j*64 + l;
            bool lt = (d[j] < bv) || (d[j] == bv && p < bi);
            if (lt) { bv = d[j]; bi = p; }
        }
        wave_reduce_min(bv, bi);
        const int win = __builtin_amdgcn_readlane(bi, 63);
        if (l == 0) kn[w*16 + r] = (u16)(win & 4095);
        #pragma unroll
        for (int j = 0; j < 64; ++j) {
            int p = j*64 + l;
            d[j] = (p == win) ? 1e38f : d[j];     // poison winner
        }
    }
    __syncthreads();                 // selection done everywhere; kn complete
    // ---- neighbor xyz from staged LDS -> registers (before overwrite) ----
    float rx = 0.f, ry = 0.f, rz = 0.f;
    if (t < 64) {
        int rp = (int)kn[t];
        rx = u.a.px[rp]; ry = u.a.py[rp]; rz = u.a.pz[rp];
    }
    __syncthreads();                 // px/py/pz reads complete -> union free
    // ---- Xs fill: points cols 0-63 (4 thr/row x 4 float4), xyz 64-66 ----
    {
        const int r = t >> 2, q = t & 3;
        const int p = (int)kn[r];
        const float* src = points + ((size_t)(bb*N_ + p))*64 + q*16;
        float4 v0 = *(const float4*)(src + 0);
        float4 v1 = *(const float4*)(src + 4);
        float4 v2 = *(const float4*)(src + 8);
        float4 v3 = *(const float4*)(src + 12);
        *(float4*)&u.b.Xs[r][q*16 + 0]  = v0;
        *(float4*)&u.b.Xs[r][q*16 + 4]  = v1;
        *(float4*)&u.b.Xs[r][q*16 + 8]  = v2;
        *(float4*)&u.b.Xs[r][q*16 + 12] = v3;
    }
    if (t < 64) {
        u.b.Xs[t][64] = rx - cen[t >> 4][0];
        u.b.Xs[t][65] = ry - cen[t >> 4][1];
        u.b.Xs[t][66] = rz - cen[t >> 4][2];
        u.b.Xs[t][67] = 0.f;
    }
    __syncthreads();
    // ---- GEMM1 (r9 64-row shape: 4 rows/thread, acc[4][8]) ----
    const int rg = t >> 4, cg = t & 15;
    const int r0 = rg * 4;
    float acc[4][8];
    #pragma unroll
    for (int j = 0; j < 4; ++j)
        #pragma unroll
        for (int i = 0; i < 8; ++i) acc[j][i] = 0.f;
    for (int q4 = 0; q4 < 17; ++q4) {
        float4 xv[4];
        #pragma unroll
        for (int j = 0; j < 4; ++j) xv[j] = *(const float4*)&u.b.Xs[r0 + j][q4*4];
        #pragma unroll
        for (int i = 0; i < 8; ++i) {
            int o = cg + 16*i;
            float w0 = g_W1T[(q4*4+0)*128 + o];
            float w1 = g_W1T[(q4*4+1)*128 + o];
            float w2 = g_W1T[(q4*4+2)*128 + o];
            float w3 = g_W1T[(q4*4+3)*128 + o];
            #pragma unroll
            for (int j = 0; j < 4; ++j) {
                float a = acc[j][i];
                a = a + xv[j].x*w0; a = a + xv[j].y*w1;
                a = a + xv[j].z*w2; a = a + xv[j].w*w3;
                acc[j][i] = a;
            }
        }
    }
    __syncthreads();   // Xs reads done -> union reusable for ps/pq
    #pragma unroll
    for (int i = 0; i < 8; ++i) {
        int o = cg + 16*i;
        float bias = b1[o];
        float s = 0.f, sq = 0.f;
        #pragma unroll
        for (int j = 0; j < 4; ++j) {
            float v = acc[j][i] + bias;
            g_h1[(size_t)(g0 + r0 + j)*128 + o] = v;
            s += v; sq += v*v;
        }
        u.b.c.ps[rg][o] = s; u.b.c.pq[rg][o] = sq;
    }
    __syncthreads();
    if (t < 128) {
        float ts = 0.f, tq = 0.f;
        #pragma unroll
        for (int g = 0; g < 16; ++g) { ts += u.b.c.ps[g][t]; tq += u.b.c.pq[g][t]; }
        const int slot = (blk & 7) * 256;
        atomicAdd(&g_statsA[slot + t], ts);
        atomicAdd(&g_statsA[slot + 128 + t], tq);
    }
}

// ------------------------------------------------ BN1+ReLU + GEMM2 ---------
// r8 retile: 128 rows/block (1024 blocks), 8 rows/thread (proven -15 us).
__global__ __launch_bounds__(256) void gemm2_kernel(
        const float* __restrict__ b2, const float* __restrict__ g1,
        const float* __restrict__ be1) {
    __shared__ float mn1[128], sc1[128], bb1[128];
    __shared__ union {
        float h1s[128][132];
        struct { float ps[16][128], pq[16][128], pm[16][128]; } c;
    } u;
    const int t = threadIdx.x;
    const int blk = blockIdx.x;
    const int g0 = blk * 128;
    if (t < 128) {
        float sum = 0.f, sq = 0.f;
        #pragma unroll
        for (int s = 0; s < 8; ++s) {
            sum += g_statsA[s*256 + t];
            sq  += g_statsA[s*256 + 128 + t];
        }
        float mean = sum * (1.f / BN_N);
        float var  = sq * (1.f / BN_N) - mean*mean;
        mn1[t] = mean; sc1[t] = (1.f / sqrtf(var + 1e-5f)) * g1[t];
        bb1[t] = be1[t];
    }
    __syncthreads();
    for (int e = t*4; e < 128*128; e += 1024) {
        float4 hv = *(const float4*)&g_h1[(size_t)g0*128 + e];
        int r = e >> 7, c = e & 127;
        u.h1s[r][c+0] = fmaxf((hv.x - mn1[c+0])*sc1[c+0] + bb1[c+0], 0.f);
        u.h1s[r][c+1] = fmaxf((hv.y - mn1[c+1])*sc1[c+1] + bb1[c+1], 0.f);
        u.h1s[r][c+2] = fmaxf((hv.z - mn1[c+2])*sc1[c+2] + bb1[c+2], 0.f);
        u.h1s[r][c+3] = fmaxf((hv.w - mn1[c+3])*sc1[c+3] + bb1[c+3], 0.f);
    }
    __syncthreads();
    const int rg = t >> 4, cg = t & 15;
    const int r0 = rg * 8;
    float acc2[8][8];
    #pragma unroll
    for (int j = 0; j < 8; ++j)
        #pragma unroll
        for (int i = 0; i < 8; ++i) acc2[j][i] = 0.f;
    for (int q4 = 0; q4 < 32; ++q4) {
        float4 xv[8];
        #pragma unroll
        for (int j = 0; j < 8; ++j) xv[j] = *(const float4*)&u.h1s[r0 + j][q4*4];
        #pragma unroll
        for (int i = 0; i < 8; ++i) {
            int o = cg + 16*i;
            float w0 = g_W2T[(q4*4+0)*128 + o];
            float w1 = g_W2T[(q4*4+1)*128 + o];
            float w2 = g_W2T[(q4*4+2)*128 + o];
            float w3 = g_W2T[(q4*4+3)*128 + o];
            #pragma unroll
            for (int j = 0; j < 8; ++j) {
                float a = acc2[j][i];
                a = a + xv[j].x*w0; a = a + xv[j].y*w1;
                a = a + xv[j].z*w2; a = a + xv[j].w*w3;
                acc2[j][i] = a;
            }
        }
    }
    __syncthreads();   // h1s reads done -> union reusable
    #pragma unroll
    for (int i = 0; i < 8; ++i) {
        int o = cg + 16*i;
        float bias = b2[o];
        float s = 0.f, sq = 0.f, mx = -1e38f;
        #pragma unroll
        for (int j = 0; j < 8; ++j) {
            float v = acc2[j][i] + bias;
            s += v; sq += v*v; mx = fmaxf(mx, v);
        }
        u.c.ps[rg][o] = s; u.c.pq[rg][o] = sq; u.c.pm[rg][o] = mx;
    }
    __syncthreads();
    if (t < 128) {
        float ts = 0.f, tq = 0.f;
        #pragma unroll
        for (int g = 0; g < 16; ++g) { ts += u.c.ps[g][t]; tq += u.c.pq[g][t]; }
        const int slot = (blk & 7) * 256;
        atomicAdd(&g_statsB[slot + t], ts);
        atomicAdd(&g_statsB[slot + 128 + t], tq);
    }
    {
        // max-pool: 128 rows = 8 output m-rows (16 input rows each);
        // pm[rg] covers rows rg*8..rg*8+7 -> m-row gm uses rg = 2gm, 2gm+1.
        const int o = t & 127, gg = t >> 7;          // gg in {0,1}
        #pragma unroll
        for (int h = 0; h < 4; ++h) {
            const int gm = h*2 + gg;                 // 0..7
            float mx = fmaxf(u.c.pm[gm*2 + 0][o], u.c.pm[gm*2 + 1][o]);
            g_m2[(blk*8 + gm)*128 + o] = mx;
        }
    }
}

// ------------------------------------------------------------- finalize ----
__global__ __launch_bounds__(256) void final_kernel(
        const float* __restrict__ g2, const float* __restrict__ be2,
        float* __restrict__ outp) {
    __shared__ float mn[128], sc[128], bb[128];
    const int t = threadIdx.x;
    if (t < 128) {
        float sum = 0.f, sq = 0.f;
        #pragma unroll
        for (int s = 0; s < 8; ++s) {
            sum += g_statsB[s*256 + t];
            sq  += g_statsB[s*256 + 128 + t];
        }
        float mean = sum * (1.f / BN_N);
        float var  = sq * (1.f / BN_N) - mean*mean;
        float inv  = 1.f / sqrtf(var + 1e-5f);
        mn[t] = mean; sc[t] = inv * g2[t]; bb[t] = be2[t];
    }
    __syncthreads();
    const int m = blockIdx.x*2 + (t >> 7);
    const int c = t & 127;
    float v = (g_m2[m*128 + c] - mn[c]) * sc[c] + bb[c];
    v = fmaxf(v, 0.f);
    outp[m*C2_ + c] = v;
}

// -------------------------------------------------------------- launch -----
extern "C" void kernel_launch(void* const* d_in, const int* in_sizes, int n_in,
                              void* d_out, int out_size, void* d_ws, size_t ws_size,
                              hipStream_t stream) {
    const float* xyz    = (const float*)d_in[0];
    const float* points = (const float*)d_in[1];
    const float* W1     = (const float*)d_in[2];
    const float* b1     = (const float*)d_in[3];
    const float* g1     = (const float*)d_in[4];
    const float* be1    = (const float*)d_in[5];
    const float* W2     = (const float*)d_in[6];
    const float* b2     = (const float*)d_in[7];
    const float* g2     = (const float*)d_in[8];
    const float* be2    = (const float*)d_in[9];

    float* out_xyz = (float*)d_out;
    float* out_pts = (float*)d_out + B_*K_*3;

    (void)d_ws; (void)ws_size;

    transpose_w_kernel<<<64, 256, 0, stream>>>(W1, W2);   // + zeroes stats
    fps_kernel<<<B_, 256, 0, stream>>>(xyz, out_xyz);
    knn_stats1_kernel<<<dim3(256, B_), 256, 0, stream>>>(xyz, points, out_xyz, b1);
    gemm2_kernel<<<NBLK2, 256, 0, stream>>>(b2, g1, be1);
    final_kernel<<<B_*K_/2, 256, 0, stream>>>(g2, be2, out_pts);
}